// Round 6
// baseline (1965.920 us; speedup 1.0000x reference)
//
#include <hip/hip_runtime.h>
#include <hip/hip_bf16.h>

typedef _Float16 half8 __attribute__((ext_vector_type(8)));
typedef float floatx4 __attribute__((ext_vector_type(4)));

// ---------------------------------------------------------------------------
// async global->LDS, 16B per lane (wave-uniform LDS base + lane*16)
__device__ inline void gload_lds16(const void* g, void* l) {
  __builtin_amdgcn_global_load_lds(
      (const __attribute__((address_space(1))) unsigned int*)g,
      (__attribute__((address_space(3))) unsigned int*)l, 16, 0, 0);
}

// LDS byte offset of a __shared__ pointer (generic -> AS3 addrspacecast)
__device__ inline unsigned lds_off(const void* p) {
  return (unsigned)(uintptr_t)(const __attribute__((address_space(3))) char*)p;
}
// Inline-asm ds_read_b128 (opaque to alias analysis; see round-4/5 notes)
__device__ inline half8 ds_read128(unsigned off) {
  half8 r;
  asm volatile("ds_read_b128 %0, %1" : "=v"(r) : "v"(off));
  return r;
}

// NOTE: no "memory" clobbers (round-3 lesson).
#define BARB()   __builtin_amdgcn_s_barrier()
#define WAITL0() asm volatile("s_waitcnt lgkmcnt(0)")
#define WAITV(n) asm volatile("s_waitcnt vmcnt(" #n ")")
#define SCHED0() __builtin_amdgcn_sched_barrier(0)

// ---------------------------------------------------------------------------
// gates[n][e] = softmax_e( x[n] . gate_w[e] + gate_b[e] )   (one wave per row)
__global__ __launch_bounds__(256) void gates_kernel(
    const float* __restrict__ x, const float* __restrict__ gw,
    const float* __restrict__ gb, float* __restrict__ gates) {
  const int lane = threadIdx.x & 63, wid = threadIdx.x >> 6;
  const int n = blockIdx.x * 4 + wid;
  const float* xr = x + (size_t)n * 1024;
  float xv[16];
#pragma unroll
  for (int i = 0; i < 16; ++i) xv[i] = xr[lane + i * 64];
  float logit[8];
#pragma unroll
  for (int e = 0; e < 8; ++e) {
    const float* wr = gw + (size_t)e * 1024;
    float p = 0.f;
#pragma unroll
    for (int i = 0; i < 16; ++i) p += xv[i] * wr[lane + i * 64];
#pragma unroll
    for (int off = 32; off > 0; off >>= 1) p += __shfl_xor(p, off);
    logit[e] = p + gb[e];
  }
  float mx = logit[0];
#pragma unroll
  for (int e = 1; e < 8; ++e) mx = fmaxf(mx, logit[e]);
  float s = 0.f;
#pragma unroll
  for (int e = 0; e < 8; ++e) { logit[e] = expf(logit[e] - mx); s += logit[e]; }
  if (lane < 8) gates[(size_t)n * 8 + lane] = logit[lane] / s;
}

// ---------------------------------------------------------------------------
// out[n][d] = sum_e gates[n][e] * b2[e][d]   (erases poison; GEMM2 atomicAdds)
__global__ __launch_bounds__(256) void bias_init_kernel(
    const float* __restrict__ gates, const float* __restrict__ b2,
    float* __restrict__ out) {
  const int idx = blockIdx.x * 256 + threadIdx.x;
  const int n = idx >> 8;
  const int d = (idx & 255) << 2;
  const float* g = gates + (size_t)n * 8;
  floatx4 acc = {0.f, 0.f, 0.f, 0.f};
#pragma unroll
  for (int e = 0; e < 8; ++e) {
    const float ge = g[e];
    const floatx4 b = *(const floatx4*)(b2 + (size_t)e * 1024 + d);
#pragma unroll
    for (int j = 0; j < 4; ++j) acc[j] += ge * b[j];
  }
  *(floatx4*)(out + (size_t)n * 1024 + d) = acc;
}

// ---------------------------------------------------------------------------
__global__ __launch_bounds__(256) void cvt_f32_f16_kernel(
    const float* __restrict__ in, _Float16* __restrict__ out, int n8) {
  const int i = blockIdx.x * 256 + threadIdx.x;
  if (i >= n8) return;
  const float4* p = (const float4*)(in + (size_t)i * 8);
  float4 a = p[0], b = p[1];
  half8 h;
  h[0] = (_Float16)a.x; h[1] = (_Float16)a.y; h[2] = (_Float16)a.z; h[3] = (_Float16)a.w;
  h[4] = (_Float16)b.x; h[5] = (_Float16)b.y; h[6] = (_Float16)b.z; h[7] = (_Float16)b.w;
  *(half8*)(out + (size_t)i * 8) = h;
}

// ---------------------------------------------------------------------------
__global__ __launch_bounds__(256) void transpose_cvt_kernel(
    const float* __restrict__ in, _Float16* __restrict__ out, int R, int C) {
  __shared__ _Float16 tile[32][33];
  const int tx = threadIdx.x & 31, ty = threadIdx.x >> 5;
  const int c0 = blockIdx.x << 5, r0 = blockIdx.y << 5;
#pragma unroll
  for (int i = 0; i < 4; ++i)
    tile[ty + i * 8][tx] = (_Float16)in[(size_t)(r0 + ty + i * 8) * C + c0 + tx];
  __syncthreads();
#pragma unroll
  for (int i = 0; i < 4; ++i)
    out[(size_t)(c0 + ty + i * 8) * R + r0 + tx] = tile[tx][ty + i * 8];
}

// ---------------------------------------------------------------------------
// 256x256-tile, BK=64, 8-phase pipelined f16 MFMA GEMM.
//   C = A[M][lda] * Bt[Nn][ldb]^T over k in [kb, kb+kLen)
// 8 waves as 2(M)x4(N); LDS 128KB = 2 buf x {A0,A1,B0,B1} 16KB regions,
// XOR-swizzled content (inverse-swizzled global src + linear DMA dest;
// swizzled asm ds_read_b128 on the read side).
// 3D XCD swizzle: 64 consecutive m-fast blocks per XCD (same n/kz chunk
// shares B-panel + A locality in that XCD's L2).
// Stage: P1:(t+1).A0  P2:(t+1).A1  P3:(t+2).B0  P4:(t+2).B1, gate vmcnt(4).
// EPI 0: Hout = relu(acc + bias)  fp16.   EPI 1: atomicAdd(Out, gate*acc).
template <int EPI>
__global__ __launch_bounds__(512, 2) void gemm256_kernel(
    const _Float16* __restrict__ A, const _Float16* __restrict__ Bt,
    const float* __restrict__ bias, const float* __restrict__ gates, int e,
    _Float16* __restrict__ Hout, float* __restrict__ Out, int lda, int ldb,
    int kLen, int Nout) {
  __shared__ _Float16 smem[2][4][8192];  // [buf][A0,A1,B0,B1][16KB]
  const int tid = threadIdx.x, lane = tid & 63, wid = tid >> 6;
  const int wm = wid >> 2, wn = wid & 3;

  // 3D bijective XCD swizzle: nb % 8 == 0 for all our grids.
  const int gx = gridDim.x, gy = gridDim.y;
  const int nb = gx * gy * gridDim.z;
  const int b = blockIdx.x + gx * (blockIdx.y + gy * blockIdx.z);
  const int s = (b & 7) * (nb >> 3) + (b >> 3);
  const int m0 = (s % gx) * 256;
  const int n0 = ((s / gx) % gy) * 256;
  const int kb = (s / (gx * gy)) * kLen;
  const int NT = kLen >> 6;

  floatx4 acc[8][4] = {};

  auto stage_half = [&](int h) {
    if (h >= 4 * NT) return;
    const int th = h >> 2, j = h & 3, bf = th & 1;
    const int k0 = kb + th * 64;
    const char* gb; int ld, rorig;
    if (j < 2) { gb = (const char*)A;  ld = lda; rorig = m0 + j * 128; }
    else       { gb = (const char*)Bt; ld = ldb; rorig = n0 + (j - 2) * 128; }
    _Float16* lb = &smem[bf][j][0];
#pragma unroll
    for (int i = 0; i < 2; ++i) {
      const int row = (wid * 2 + i) * 8 + (lane >> 3);
      const int gkb = ((lane & 7) * 16) ^ ((row & 7) << 4);  // inverse swizzle
      gload_lds16(gb + ((size_t)(rorig + row) * ld + k0) * 2 + gkb,
                  lb + (wid * 2 + i) * 512 + lane * 8);
    }
  };

  const unsigned smem0 = lds_off(&smem[0][0][0]);
  auto ldA = [&](int bf, int mf, int ks) -> half8 {
    const int row = mf * 16 + (lane & 15);
    const int col = (ks * 64 + ((lane >> 4) << 4)) ^ ((row & 7) << 4);
    return ds_read128(smem0 + (bf * 4 + wm) * 16384 + row * 128 + col);
  };
  auto ldB = [&](int bf, int nf, int ks) -> half8 {
    const int c = wn * 64 + nf * 16 + (lane & 15);
    const int r = c & 127;
    const int col = (ks * 64 + ((lane >> 4) << 4)) ^ ((r & 7) << 4);
    return ds_read128(smem0 + (bf * 4 + 2 + (c >> 7)) * 16384 + r * 128 + col);
  };

  // prologue: tile0 all 4 halves + tile1.B0/B1; leave tile1.B* in flight
  stage_half(0); stage_half(1); stage_half(2); stage_half(3);
  stage_half(4 * 1 + 2); stage_half(4 * 1 + 3);
  WAITV(4); SCHED0();
  BARB();

#pragma unroll 1
  for (int t = 0; t < NT; ++t) {
    const int bf = t & 1;
    half8 a[4][2], bh[2][2], bl[2][2];
    // ---- P1: read A m0-3 + B hi; stage (t+1).A0; MFMA m0-3 x n2-3
#pragma unroll
    for (int ks = 0; ks < 2; ++ks) {
#pragma unroll
      for (int m = 0; m < 4; ++m) a[m][ks] = ldA(bf, m, ks);
#pragma unroll
      for (int n = 0; n < 2; ++n) bh[n][ks] = ldB(bf, 2 + n, ks);
    }
    stage_half(4 * (t + 1) + 0);
    BARB(); WAITL0(); SCHED0();
    __builtin_amdgcn_s_setprio(1);
#pragma unroll
    for (int m = 0; m < 4; ++m)
#pragma unroll
      for (int n = 0; n < 2; ++n)
#pragma unroll
        for (int ks = 0; ks < 2; ++ks)
          acc[m][2 + n] = __builtin_amdgcn_mfma_f32_16x16x32_f16(
              a[m][ks], bh[n][ks], acc[m][2 + n], 0, 0, 0);
    __builtin_amdgcn_s_setprio(0);
    BARB();
    // ---- P2: read B lo; stage (t+1).A1; MFMA m0-3 x n0-1
#pragma unroll
    for (int ks = 0; ks < 2; ++ks)
#pragma unroll
      for (int n = 0; n < 2; ++n) bl[n][ks] = ldB(bf, n, ks);
    stage_half(4 * (t + 1) + 1);
    BARB(); WAITL0(); SCHED0();
    __builtin_amdgcn_s_setprio(1);
#pragma unroll
    for (int m = 0; m < 4; ++m)
#pragma unroll
      for (int n = 0; n < 2; ++n)
#pragma unroll
        for (int ks = 0; ks < 2; ++ks)
          acc[m][n] = __builtin_amdgcn_mfma_f32_16x16x32_f16(
              a[m][ks], bl[n][ks], acc[m][n], 0, 0, 0);
    __builtin_amdgcn_s_setprio(0);
    BARB();
    // ---- P3: read A m4-7; stage (t+2).B0; MFMA m4-7 x n2-3
#pragma unroll
    for (int ks = 0; ks < 2; ++ks)
#pragma unroll
      for (int m = 0; m < 4; ++m) a[m][ks] = ldA(bf, 4 + m, ks);
    stage_half(4 * (t + 2) + 2);
    BARB(); WAITL0(); SCHED0();
    __builtin_amdgcn_s_setprio(1);
#pragma unroll
    for (int m = 0; m < 4; ++m)
#pragma unroll
      for (int n = 0; n < 2; ++n)
#pragma unroll
        for (int ks = 0; ks < 2; ++ks)
          acc[4 + m][2 + n] = __builtin_amdgcn_mfma_f32_16x16x32_f16(
              a[m][ks], bh[n][ks], acc[4 + m][2 + n], 0, 0, 0);
    __builtin_amdgcn_s_setprio(0);
    BARB();
    // ---- P4: stage (t+2).B1; MFMA m4-7 x n0-1; counted gate; release
    stage_half(4 * (t + 2) + 3);
    BARB();
    __builtin_amdgcn_s_setprio(1);
#pragma unroll
    for (int m = 0; m < 4; ++m)
#pragma unroll
      for (int n = 0; n < 2; ++n)
#pragma unroll
        for (int ks = 0; ks < 2; ++ks)
          acc[4 + m][n] = __builtin_amdgcn_mfma_f32_16x16x32_f16(
              a[m][ks], bl[n][ks], acc[4 + m][n], 0, 0, 0);
    __builtin_amdgcn_s_setprio(0);
    if (t + 2 < NT) { WAITV(4); } else { WAITV(0); }  // tail: drain all
    SCHED0();
    BARB();
  }

  // epilogue: D-frag col = lane&15, row = (lane>>4)*4 + r
#pragma unroll
  for (int mf = 0; mf < 8; ++mf) {
    const int gr0 = m0 + wm * 128 + mf * 16 + ((lane >> 4) << 2);
#pragma unroll
    for (int nf = 0; nf < 4; ++nf) {
      const int gc = n0 + wn * 64 + nf * 16 + (lane & 15);
#pragma unroll
      for (int r = 0; r < 4; ++r) {
        const int gr = gr0 + r;
        if (EPI == 0) {
          const float v = acc[mf][nf][r] + bias[gc];
          Hout[(size_t)gr * Nout + gc] = (_Float16)fmaxf(v, 0.0f);
        } else {
          atomicAdd(Out + (size_t)gr * Nout + gc,
                    gates[(size_t)gr * 8 + e] * acc[mf][nf][r]);
        }
      }
    }
  }
}

// ---------------------------------------------------------------------------
extern "C" void kernel_launch(void* const* d_in, const int* in_sizes, int n_in,
                              void* d_out, int out_size, void* d_ws,
                              size_t ws_size, hipStream_t stream) {
  const float* x  = (const float*)d_in[0];
  const float* gw = (const float*)d_in[1];
  const float* gb = (const float*)d_in[2];
  const float* w1 = (const float*)d_in[3];
  const float* b1 = (const float*)d_in[4];
  const float* w2 = (const float*)d_in[5];
  const float* b2 = (const float*)d_in[6];
  float* out = (float*)d_out;

  const int N = 8192, D = 1024, H = 4096, E = 8;

  char* ws = (char*)d_ws;
  float* gates   = (float*)ws;                                     // 256 KB
  _Float16* x_h  = (_Float16*)(ws + (1ull << 20));                 // 16 MB
  _Float16* w1t  = (_Float16*)(ws + (1ull << 20) + (16ull << 20)); // 8 MB  [H][D]
  _Float16* w2t  = (_Float16*)(ws + (1ull << 20) + (24ull << 20)); // 8 MB  [D][H]
  _Float16* Hbuf = (_Float16*)(ws + (1ull << 20) + (32ull << 20)); // 64 MB [N][H]

  gates_kernel<<<N / 4, 256, 0, stream>>>(x, gw, gb, gates);
  bias_init_kernel<<<N * D / 4 / 256, 256, 0, stream>>>(gates, b2, out);
  cvt_f32_f16_kernel<<<(N * D / 8 + 255) / 256, 256, 0, stream>>>(x, x_h, N * D / 8);

  for (int e = 0; e < E; ++e) {
    transpose_cvt_kernel<<<dim3(H / 32, D / 32), 256, 0, stream>>>(
        w1 + (size_t)e * D * H, w1t, D, H);
    transpose_cvt_kernel<<<dim3(D / 32, H / 32), 256, 0, stream>>>(
        w2 + (size_t)e * H * D, w2t, H, D);
    // GEMM1: [8192,1024] x [4096,1024]^T -> relu(+b1) -> Hbuf fp16 [N][H]
    gemm256_kernel<0><<<dim3(N / 256, H / 256, 1), 512, 0, stream>>>(
        x_h, w1t, b1 + (size_t)e * H, nullptr, e, Hbuf, nullptr, D, D, D, H);
    // GEMM2: [8192,4096] x [1024,4096]^T, split-K x4, gated atomic accumulate
    gemm256_kernel<1><<<dim3(N / 256, D / 256, 4), 512, 0, stream>>>(
        Hbuf, w2t, nullptr, gates, e, nullptr, out, H, H, H / 4, D);
  }
}

// Round 7
// 1475.095 us; speedup vs baseline: 1.3327x; 1.3327x over previous
//
#include <hip/hip_runtime.h>
#include <hip/hip_bf16.h>

typedef _Float16 half8 __attribute__((ext_vector_type(8)));
typedef float floatx4 __attribute__((ext_vector_type(4)));

// ---------------------------------------------------------------------------
// async global->LDS, 16B per lane (wave-uniform LDS base + lane*16)
__device__ inline void gload_lds16(const void* g, void* l) {
  __builtin_amdgcn_global_load_lds(
      (const __attribute__((address_space(1))) unsigned int*)g,
      (__attribute__((address_space(3))) unsigned int*)l, 16, 0, 0);
}

// LDS byte offset of a __shared__ pointer (generic -> AS3 addrspacecast)
__device__ inline unsigned lds_off(const void* p) {
  return (unsigned)(uintptr_t)(const __attribute__((address_space(3))) char*)p;
}
// Inline-asm ds_read_b128 (opaque to alias analysis; round-4/5 notes)
__device__ inline half8 ds_read128(unsigned off) {
  half8 r;
  asm volatile("ds_read_b128 %0, %1" : "=v"(r) : "v"(off));
  return r;
}

// NOTE: no "memory" clobbers (round-3 lesson).
#define BARB()   __builtin_amdgcn_s_barrier()
#define WAITL0() asm volatile("s_waitcnt lgkmcnt(0)")
#define WAITV(n) asm volatile("s_waitcnt vmcnt(" #n ")")
#define SCHED0() __builtin_amdgcn_sched_barrier(0)

// ---------------------------------------------------------------------------
// gates[n][e] = softmax_e( x[n] . gate_w[e] + gate_b[e] )   (one wave per row)
__global__ __launch_bounds__(256) void gates_kernel(
    const float* __restrict__ x, const float* __restrict__ gw,
    const float* __restrict__ gb, float* __restrict__ gates) {
  const int lane = threadIdx.x & 63, wid = threadIdx.x >> 6;
  const int n = blockIdx.x * 4 + wid;
  const float* xr = x + (size_t)n * 1024;
  float xv[16];
#pragma unroll
  for (int i = 0; i < 16; ++i) xv[i] = xr[lane + i * 64];
  float logit[8];
#pragma unroll
  for (int e = 0; e < 8; ++e) {
    const float* wr = gw + (size_t)e * 1024;
    float p = 0.f;
#pragma unroll
    for (int i = 0; i < 16; ++i) p += xv[i] * wr[lane + i * 64];
#pragma unroll
    for (int off = 32; off > 0; off >>= 1) p += __shfl_xor(p, off);
    logit[e] = p + gb[e];
  }
  float mx = logit[0];
#pragma unroll
  for (int e = 1; e < 8; ++e) mx = fmaxf(mx, logit[e]);
  float s = 0.f;
#pragma unroll
  for (int e = 0; e < 8; ++e) { logit[e] = expf(logit[e] - mx); s += logit[e]; }
  if (lane < 8) gates[(size_t)n * 8 + lane] = logit[lane] / s;
}

// ---------------------------------------------------------------------------
// out[n][d] = sum_e gates[n][e] * b2[e][d]   (erases poison; GEMM2 RMW-adds)
__global__ __launch_bounds__(256) void bias_init_kernel(
    const float* __restrict__ gates, const float* __restrict__ b2,
    float* __restrict__ out) {
  const int idx = blockIdx.x * 256 + threadIdx.x;
  const int n = idx >> 8;
  const int d = (idx & 255) << 2;
  const float* g = gates + (size_t)n * 8;
  floatx4 acc = {0.f, 0.f, 0.f, 0.f};
#pragma unroll
  for (int e = 0; e < 8; ++e) {
    const float ge = g[e];
    const floatx4 b = *(const floatx4*)(b2 + (size_t)e * 1024 + d);
#pragma unroll
    for (int j = 0; j < 4; ++j) acc[j] += ge * b[j];
  }
  *(floatx4*)(out + (size_t)n * 1024 + d) = acc;
}

// ---------------------------------------------------------------------------
__global__ __launch_bounds__(256) void cvt_f32_f16_kernel(
    const float* __restrict__ in, _Float16* __restrict__ out, int n8) {
  const int i = blockIdx.x * 256 + threadIdx.x;
  if (i >= n8) return;
  const float4* p = (const float4*)(in + (size_t)i * 8);
  float4 a = p[0], b = p[1];
  half8 h;
  h[0] = (_Float16)a.x; h[1] = (_Float16)a.y; h[2] = (_Float16)a.z; h[3] = (_Float16)a.w;
  h[4] = (_Float16)b.x; h[5] = (_Float16)b.y; h[6] = (_Float16)b.z; h[7] = (_Float16)b.w;
  *(half8*)(out + (size_t)i * 8) = h;
}

// ---------------------------------------------------------------------------
__global__ __launch_bounds__(256) void transpose_cvt_kernel(
    const float* __restrict__ in, _Float16* __restrict__ out, int R, int C) {
  __shared__ _Float16 tile[32][33];
  const int tx = threadIdx.x & 31, ty = threadIdx.x >> 5;
  const int c0 = blockIdx.x << 5, r0 = blockIdx.y << 5;
#pragma unroll
  for (int i = 0; i < 4; ++i)
    tile[ty + i * 8][tx] = (_Float16)in[(size_t)(r0 + ty + i * 8) * C + c0 + tx];
  __syncthreads();
#pragma unroll
  for (int i = 0; i < 4; ++i)
    out[(size_t)(c0 + ty + i * 8) * R + r0 + tx] = tile[tx][ty + i * 8];
}

// ---------------------------------------------------------------------------
// GEMM1: 256x256-tile, BK=64, 8-phase pipelined f16 MFMA GEMM.
//   Hout[n][h] = gates[n][e] * relu(A.Bt^T + bias)   (gate folded in!)
// Structure identical to round-5/6 kernel (see those notes).
__global__ __launch_bounds__(512, 2) void gemm1_kernel(
    const _Float16* __restrict__ A, const _Float16* __restrict__ Bt,
    const float* __restrict__ bias, const float* __restrict__ gates, int e,
    _Float16* __restrict__ Hout, int lda, int ldb, int K, int Nout) {
  __shared__ _Float16 smem[2][4][8192];  // [buf][A0,A1,B0,B1][16KB]
  const int tid = threadIdx.x, lane = tid & 63, wid = tid >> 6;
  const int wm = wid >> 2, wn = wid & 3;

  const int gx = gridDim.x;
  const int nb = gx * gridDim.y;
  const int b = blockIdx.x + gx * blockIdx.y;
  const int s = (b & 7) * (nb >> 3) + (b >> 3);
  const int m0 = (s % gx) * 256;
  const int n0 = (s / gx) * 256;
  const int NT = K >> 6;

  floatx4 acc[8][4] = {};

  auto stage_half = [&](int h) {
    if (h >= 4 * NT) return;
    const int th = h >> 2, j = h & 3, bf = th & 1;
    const int k0 = th * 64;
    const char* gb; int ld, rorig;
    if (j < 2) { gb = (const char*)A;  ld = lda; rorig = m0 + j * 128; }
    else       { gb = (const char*)Bt; ld = ldb; rorig = n0 + (j - 2) * 128; }
    _Float16* lb = &smem[bf][j][0];
#pragma unroll
    for (int i = 0; i < 2; ++i) {
      const int row = (wid * 2 + i) * 8 + (lane >> 3);
      const int gkb = ((lane & 7) * 16) ^ ((row & 7) << 4);  // inverse swizzle
      gload_lds16(gb + ((size_t)(rorig + row) * ld + k0) * 2 + gkb,
                  lb + (wid * 2 + i) * 512 + lane * 8);
    }
  };

  const unsigned smem0 = lds_off(&smem[0][0][0]);
  auto ldA = [&](int bf, int mf, int ks) -> half8 {
    const int row = mf * 16 + (lane & 15);
    const int col = (ks * 64 + ((lane >> 4) << 4)) ^ ((row & 7) << 4);
    return ds_read128(smem0 + (bf * 4 + wm) * 16384 + row * 128 + col);
  };
  auto ldB = [&](int bf, int nf, int ks) -> half8 {
    const int c = wn * 64 + nf * 16 + (lane & 15);
    const int r = c & 127;
    const int col = (ks * 64 + ((lane >> 4) << 4)) ^ ((r & 7) << 4);
    return ds_read128(smem0 + (bf * 4 + 2 + (c >> 7)) * 16384 + r * 128 + col);
  };

  stage_half(0); stage_half(1); stage_half(2); stage_half(3);
  stage_half(4 * 1 + 2); stage_half(4 * 1 + 3);
  WAITV(4); SCHED0();
  BARB();

#pragma unroll 1
  for (int t = 0; t < NT; ++t) {
    const int bf = t & 1;
    half8 a[4][2], bh[2][2], bl[2][2];
    // ---- P1
#pragma unroll
    for (int ks = 0; ks < 2; ++ks) {
#pragma unroll
      for (int m = 0; m < 4; ++m) a[m][ks] = ldA(bf, m, ks);
#pragma unroll
      for (int n = 0; n < 2; ++n) bh[n][ks] = ldB(bf, 2 + n, ks);
    }
    stage_half(4 * (t + 1) + 0);
    BARB(); WAITL0(); SCHED0();
    __builtin_amdgcn_s_setprio(1);
#pragma unroll
    for (int m = 0; m < 4; ++m)
#pragma unroll
      for (int n = 0; n < 2; ++n)
#pragma unroll
        for (int ks = 0; ks < 2; ++ks)
          acc[m][2 + n] = __builtin_amdgcn_mfma_f32_16x16x32_f16(
              a[m][ks], bh[n][ks], acc[m][2 + n], 0, 0, 0);
    __builtin_amdgcn_s_setprio(0);
    BARB();
    // ---- P2
#pragma unroll
    for (int ks = 0; ks < 2; ++ks)
#pragma unroll
      for (int n = 0; n < 2; ++n) bl[n][ks] = ldB(bf, n, ks);
    stage_half(4 * (t + 1) + 1);
    BARB(); WAITL0(); SCHED0();
    __builtin_amdgcn_s_setprio(1);
#pragma unroll
    for (int m = 0; m < 4; ++m)
#pragma unroll
      for (int n = 0; n < 2; ++n)
#pragma unroll
        for (int ks = 0; ks < 2; ++ks)
          acc[m][n] = __builtin_amdgcn_mfma_f32_16x16x32_f16(
              a[m][ks], bl[n][ks], acc[m][n], 0, 0, 0);
    __builtin_amdgcn_s_setprio(0);
    BARB();
    // ---- P3
#pragma unroll
    for (int ks = 0; ks < 2; ++ks)
#pragma unroll
      for (int m = 0; m < 4; ++m) a[m][ks] = ldA(bf, 4 + m, ks);
    stage_half(4 * (t + 2) + 2);
    BARB(); WAITL0(); SCHED0();
    __builtin_amdgcn_s_setprio(1);
#pragma unroll
    for (int m = 0; m < 4; ++m)
#pragma unroll
      for (int n = 0; n < 2; ++n)
#pragma unroll
        for (int ks = 0; ks < 2; ++ks)
          acc[4 + m][2 + n] = __builtin_amdgcn_mfma_f32_16x16x32_f16(
              a[m][ks], bh[n][ks], acc[4 + m][2 + n], 0, 0, 0);
    __builtin_amdgcn_s_setprio(0);
    BARB();
    // ---- P4
    stage_half(4 * (t + 2) + 3);
    BARB();
    __builtin_amdgcn_s_setprio(1);
#pragma unroll
    for (int m = 0; m < 4; ++m)
#pragma unroll
      for (int n = 0; n < 2; ++n)
#pragma unroll
        for (int ks = 0; ks < 2; ++ks)
          acc[4 + m][n] = __builtin_amdgcn_mfma_f32_16x16x32_f16(
              a[m][ks], bl[n][ks], acc[4 + m][n], 0, 0, 0);
    __builtin_amdgcn_s_setprio(0);
    if (t + 2 < NT) { WAITV(4); } else { WAITV(0); }
    SCHED0();
    BARB();
  }

  // epilogue: Hout = gate * relu(acc + bias)
#pragma unroll
  for (int mf = 0; mf < 8; ++mf) {
    const int gr0 = m0 + wm * 128 + mf * 16 + ((lane >> 4) << 2);
#pragma unroll
    for (int r = 0; r < 4; ++r) {
      const float g = gates[(size_t)(gr0 + r) * 8 + e];
#pragma unroll
      for (int nf = 0; nf < 4; ++nf) {
        const int gc = n0 + wn * 64 + nf * 16 + (lane & 15);
        const float v = acc[mf][nf][r] + bias[gc];
        Hout[(size_t)(gr0 + r) * Nout + gc] = (_Float16)(g * fmaxf(v, 0.0f));
      }
    }
  }
}

// ---------------------------------------------------------------------------
// GEMM2: 256x128-tile, BK=64, 2-phase pipelined, ring-of-3 LDS, NO atomics.
//   Out[m][n] += A[m][k] * Bt[n][k]^T   (exclusive owner per out element;
//   gate already folded into A = Hbuf'; bias term pre-added by bias_init)
// 8 waves as 2(M)x4(N), per-wave 128x32. LDS 144KB = 3 ring bufs x
// {A0[128][64], A1[128][64], B[128][64]} 16KB regions, XOR-swizzled.
// Stage: tile t stages (t+2).{A0,A1} in P1, (t+2).B in P2; gate vmcnt(6)
// at P2 end (= the 6 loads of tile t+2 stay in flight; tile t+1 arrived).
__global__ __launch_bounds__(512, 2) void gemm2_kernel(
    const _Float16* __restrict__ A, const _Float16* __restrict__ Bt,
    float* __restrict__ Out, int lda, int ldb, int K, int Nout) {
  __shared__ _Float16 smem[3][3][8192];  // [ring][A0,A1,B][16KB]
  const int tid = threadIdx.x, lane = tid & 63, wid = tid >> 6;
  const int wm = wid >> 2, wn = wid & 3;

  const int gx = gridDim.x;
  const int nb = gx * gridDim.y;
  const int b = blockIdx.x + gx * blockIdx.y;
  const int s = (b & 7) * (nb >> 3) + (b >> 3);
  const int m0 = (s % gx) * 256;
  const int n0 = (s / gx) * 128;
  const int NT = K >> 6;

  floatx4 acc[8][2] = {};

  auto stage_half = [&](int tile, int j) {
    if (tile >= NT) return;
    const int bf = tile % 3;
    const int k0 = tile * 64;
    const char* gb; int ld, rorig;
    if (j < 2) { gb = (const char*)A;  ld = lda; rorig = m0 + j * 128; }
    else       { gb = (const char*)Bt; ld = ldb; rorig = n0; }
    _Float16* lb = &smem[bf][j][0];
#pragma unroll
    for (int i = 0; i < 2; ++i) {
      const int row = (wid * 2 + i) * 8 + (lane >> 3);
      const int gkb = ((lane & 7) * 16) ^ ((row & 7) << 4);  // inverse swizzle
      gload_lds16(gb + ((size_t)(rorig + row) * ld + k0) * 2 + gkb,
                  lb + (wid * 2 + i) * 512 + lane * 8);
    }
  };

  const unsigned smem0 = lds_off(&smem[0][0][0]);
  auto ldA = [&](int bf, int mf, int ks) -> half8 {
    const int row = mf * 16 + (lane & 15);
    const int col = (ks * 64 + ((lane >> 4) << 4)) ^ ((row & 7) << 4);
    return ds_read128(smem0 + (bf * 3 + wm) * 16384 + row * 128 + col);
  };
  auto ldB = [&](int bf, int nf, int ks) -> half8 {
    const int r = wn * 32 + nf * 16 + (lane & 15);
    const int col = (ks * 64 + ((lane >> 4) << 4)) ^ ((r & 7) << 4);
    return ds_read128(smem0 + (bf * 3 + 2) * 16384 + r * 128 + col);
  };

  // prologue: stage tiles 0,1 fully; wait tile0 (tile1's 6 loads in flight)
  stage_half(0, 0); stage_half(0, 1); stage_half(0, 2);
  stage_half(1, 0); stage_half(1, 1); stage_half(1, 2);
  WAITV(6); SCHED0();
  BARB();

#pragma unroll 1
  for (int t = 0; t < NT; ++t) {
    const int bf = t % 3;
    half8 a[4][2], bb[2][2];
    // ---- P1: read A m0-3 + B; stage (t+2).A0/A1; MFMA m0-3
#pragma unroll
    for (int ks = 0; ks < 2; ++ks) {
#pragma unroll
      for (int m = 0; m < 4; ++m) a[m][ks] = ldA(bf, m, ks);
#pragma unroll
      for (int n = 0; n < 2; ++n) bb[n][ks] = ldB(bf, n, ks);
    }
    stage_half(t + 2, 0); stage_half(t + 2, 1);
    BARB(); WAITL0(); SCHED0();
    __builtin_amdgcn_s_setprio(1);
#pragma unroll
    for (int m = 0; m < 4; ++m)
#pragma unroll
      for (int n = 0; n < 2; ++n)
#pragma unroll
        for (int ks = 0; ks < 2; ++ks)
          acc[m][n] = __builtin_amdgcn_mfma_f32_16x16x32_f16(
              a[m][ks], bb[n][ks], acc[m][n], 0, 0, 0);
    __builtin_amdgcn_s_setprio(0);
    BARB();
    // ---- P2: read A m4-7; stage (t+2).B; MFMA m4-7; counted gate
#pragma unroll
    for (int ks = 0; ks < 2; ++ks)
#pragma unroll
      for (int m = 0; m < 4; ++m) a[m][ks] = ldA(bf, 4 + m, ks);
    stage_half(t + 2, 2);
    BARB(); WAITL0(); SCHED0();
    __builtin_amdgcn_s_setprio(1);
#pragma unroll
    for (int m = 0; m < 4; ++m)
#pragma unroll
      for (int n = 0; n < 2; ++n)
#pragma unroll
        for (int ks = 0; ks < 2; ++ks)
          acc[4 + m][n] = __builtin_amdgcn_mfma_f32_16x16x32_f16(
              a[m][ks], bb[n][ks], acc[4 + m][n], 0, 0, 0);
    __builtin_amdgcn_s_setprio(0);
    if (t + 2 < NT) { WAITV(6); } else { WAITV(0); }
    SCHED0();
    BARB();
  }

  // epilogue: Out += acc (exclusive owner; stream order serializes experts)
#pragma unroll
  for (int mf = 0; mf < 8; ++mf) {
    const int gr0 = m0 + wm * 128 + mf * 16 + ((lane >> 4) << 2);
#pragma unroll
    for (int nf = 0; nf < 2; ++nf) {
      const int gc = n0 + wn * 32 + nf * 16 + (lane & 15);
#pragma unroll
      for (int r = 0; r < 4; ++r) {
        float* p = Out + (size_t)(gr0 + r) * Nout + gc;
        *p = *p + acc[mf][nf][r];
      }
    }
  }
}

// ---------------------------------------------------------------------------
extern "C" void kernel_launch(void* const* d_in, const int* in_sizes, int n_in,
                              void* d_out, int out_size, void* d_ws,
                              size_t ws_size, hipStream_t stream) {
  const float* x  = (const float*)d_in[0];
  const float* gw = (const float*)d_in[1];
  const float* gb = (const float*)d_in[2];
  const float* w1 = (const float*)d_in[3];
  const float* b1 = (const float*)d_in[4];
  const float* w2 = (const float*)d_in[5];
  const float* b2 = (const float*)d_in[6];
  float* out = (float*)d_out;

  const int N = 8192, D = 1024, H = 4096, E = 8;

  char* ws = (char*)d_ws;
  float* gates   = (float*)ws;                                     // 256 KB
  _Float16* x_h  = (_Float16*)(ws + (1ull << 20));                 // 16 MB
  _Float16* w1t  = (_Float16*)(ws + (1ull << 20) + (16ull << 20)); // 8 MB  [H][D]
  _Float16* w2t  = (_Float16*)(ws + (1ull << 20) + (24ull << 20)); // 8 MB  [D][H]
  _Float16* Hbuf = (_Float16*)(ws + (1ull << 20) + (32ull << 20)); // 64 MB [N][H]

  gates_kernel<<<N / 4, 256, 0, stream>>>(x, gw, gb, gates);
  bias_init_kernel<<<N * D / 4 / 256, 256, 0, stream>>>(gates, b2, out);
  cvt_f32_f16_kernel<<<(N * D / 8 + 255) / 256, 256, 0, stream>>>(x, x_h, N * D / 8);

  for (int e = 0; e < E; ++e) {
    transpose_cvt_kernel<<<dim3(H / 32, D / 32), 256, 0, stream>>>(
        w1 + (size_t)e * D * H, w1t, D, H);
    transpose_cvt_kernel<<<dim3(D / 32, H / 32), 256, 0, stream>>>(
        w2 + (size_t)e * H * D, w2t, H, D);
    // GEMM1: Hbuf[n,h] = gates[n,e] * relu(x.w1t^T + b1)   fp16
    gemm1_kernel<<<dim3(N / 256, H / 256), 512, 0, stream>>>(
        x_h, w1t, b1 + (size_t)e * H, gates, e, Hbuf, D, D, D, H);
    // GEMM2: out += Hbuf.w2t^T   (no atomics, exclusive owner per element)
    gemm2_kernel<<<dim3(N / 256, D / 128), 512, 0, stream>>>(
        Hbuf, w2t, out, H, H, H, D);
  }
}

// Round 8
// 1378.685 us; speedup vs baseline: 1.4259x; 1.0699x over previous
//
#include <hip/hip_runtime.h>
#include <hip/hip_bf16.h>

typedef _Float16 half8 __attribute__((ext_vector_type(8)));
typedef float floatx4 __attribute__((ext_vector_type(4)));

// ---------------------------------------------------------------------------
// async global->LDS, 16B per lane (wave-uniform LDS base + lane*16)
__device__ inline void gload_lds16(const void* g, void* l) {
  __builtin_amdgcn_global_load_lds(
      (const __attribute__((address_space(1))) unsigned int*)g,
      (__attribute__((address_space(3))) unsigned int*)l, 16, 0, 0);
}

// LDS byte offset of a __shared__ pointer (generic -> AS3 addrspacecast)
__device__ inline unsigned lds_off(const void* p) {
  return (unsigned)(uintptr_t)(const __attribute__((address_space(3))) char*)p;
}
// Inline-asm ds_read_b128 (opaque to alias analysis; round-4/5 notes)
__device__ inline half8 ds_read128(unsigned off) {
  half8 r;
  asm volatile("ds_read_b128 %0, %1" : "=v"(r) : "v"(off));
  return r;
}

// NOTE: no "memory" clobbers (round-3 lesson).
#define BARB()   __builtin_amdgcn_s_barrier()
#define WAITL0() asm volatile("s_waitcnt lgkmcnt(0)")
#define WAITV(n) asm volatile("s_waitcnt vmcnt(" #n ")")
#define SCHED0() __builtin_amdgcn_sched_barrier(0)

// Panel-chunked n-fast XCD swizzle (round-8): each XCD owns a 2D chunk of
// the block grid (nb/8 blocks = [chunk_m x 8n] panel), so its L2 sees a
// small unique A-panel + B-panel instead of all of A (round-7: every XCD
// streamed the whole 64MB Hbuf -> 283MB L2-fill).  Requires nb%8==0 and
// gridDim.y%8==0 || gridDim.y==8.
__device__ inline void xcd_chunk_decode(int* mb, int* nk) {
  const int gx = gridDim.x;
  const int nb = gx * gridDim.y;
  const int b = blockIdx.x + gx * blockIdx.y;
  const int s = (b & 7) * (nb >> 3) + (b >> 3);  // bijective
  const int PW = gx * 8;                         // panel = gx m-blocks x 8 n
  const int p = s / PW, r = s % PW;              // n-fast within panel
  *mb = r >> 3;
  *nk = p * 8 + (r & 7);
}

// ---------------------------------------------------------------------------
// gates[n][e] = softmax_e( x[n] . gate_w[e] + gate_b[e] )   (one wave per row)
__global__ __launch_bounds__(256) void gates_kernel(
    const float* __restrict__ x, const float* __restrict__ gw,
    const float* __restrict__ gb, float* __restrict__ gates) {
  const int lane = threadIdx.x & 63, wid = threadIdx.x >> 6;
  const int n = blockIdx.x * 4 + wid;
  const float* xr = x + (size_t)n * 1024;
  float xv[16];
#pragma unroll
  for (int i = 0; i < 16; ++i) xv[i] = xr[lane + i * 64];
  float logit[8];
#pragma unroll
  for (int e = 0; e < 8; ++e) {
    const float* wr = gw + (size_t)e * 1024;
    float p = 0.f;
#pragma unroll
    for (int i = 0; i < 16; ++i) p += xv[i] * wr[lane + i * 64];
#pragma unroll
    for (int off = 32; off > 0; off >>= 1) p += __shfl_xor(p, off);
    logit[e] = p + gb[e];
  }
  float mx = logit[0];
#pragma unroll
  for (int e = 1; e < 8; ++e) mx = fmaxf(mx, logit[e]);
  float s = 0.f;
#pragma unroll
  for (int e = 0; e < 8; ++e) { logit[e] = expf(logit[e] - mx); s += logit[e]; }
  if (lane < 8) gates[(size_t)n * 8 + lane] = logit[lane] / s;
}

// ---------------------------------------------------------------------------
// out[n][d] = sum_e gates[n][e] * b2[e][d]   (erases poison; GEMM2 RMW-adds)
__global__ __launch_bounds__(256) void bias_init_kernel(
    const float* __restrict__ gates, const float* __restrict__ b2,
    float* __restrict__ out) {
  const int idx = blockIdx.x * 256 + threadIdx.x;
  const int n = idx >> 8;
  const int d = (idx & 255) << 2;
  const float* g = gates + (size_t)n * 8;
  floatx4 acc = {0.f, 0.f, 0.f, 0.f};
#pragma unroll
  for (int e = 0; e < 8; ++e) {
    const float ge = g[e];
    const floatx4 b = *(const floatx4*)(b2 + (size_t)e * 1024 + d);
#pragma unroll
    for (int j = 0; j < 4; ++j) acc[j] += ge * b[j];
  }
  *(floatx4*)(out + (size_t)n * 1024 + d) = acc;
}

// ---------------------------------------------------------------------------
__global__ __launch_bounds__(256) void cvt_f32_f16_kernel(
    const float* __restrict__ in, _Float16* __restrict__ out, int n8) {
  const int i = blockIdx.x * 256 + threadIdx.x;
  if (i >= n8) return;
  const float4* p = (const float4*)(in + (size_t)i * 8);
  float4 a = p[0], b = p[1];
  half8 h;
  h[0] = (_Float16)a.x; h[1] = (_Float16)a.y; h[2] = (_Float16)a.z; h[3] = (_Float16)a.w;
  h[4] = (_Float16)b.x; h[5] = (_Float16)b.y; h[6] = (_Float16)b.z; h[7] = (_Float16)b.w;
  *(half8*)(out + (size_t)i * 8) = h;
}

// ---------------------------------------------------------------------------
// batched: out[z][c][r] = (fp16) in[z][r][c]
__global__ __launch_bounds__(256) void transpose_cvt_kernel(
    const float* __restrict__ in, _Float16* __restrict__ out, int R, int C) {
  __shared__ _Float16 tile[32][33];
  const float* src = in + (size_t)blockIdx.z * R * C;
  _Float16* dst = out + (size_t)blockIdx.z * R * C;
  const int tx = threadIdx.x & 31, ty = threadIdx.x >> 5;
  const int c0 = blockIdx.x << 5, r0 = blockIdx.y << 5;
#pragma unroll
  for (int i = 0; i < 4; ++i)
    tile[ty + i * 8][tx] = (_Float16)src[(size_t)(r0 + ty + i * 8) * C + c0 + tx];
  __syncthreads();
#pragma unroll
  for (int i = 0; i < 4; ++i)
    dst[(size_t)(c0 + ty + i * 8) * R + r0 + tx] = tile[tx][ty + i * 8];
}

// ---------------------------------------------------------------------------
// GEMM1: 256x256-tile, BK=64, 8-phase pipelined f16 MFMA GEMM.
//   Hout[n][h] = gates[n][e] * relu(A.Bt^T + bias)   (gate folded in)
__global__ __launch_bounds__(512, 2) void gemm1_kernel(
    const _Float16* __restrict__ A, const _Float16* __restrict__ Bt,
    const float* __restrict__ bias, const float* __restrict__ gates, int e,
    _Float16* __restrict__ Hout, int lda, int ldb, int K, int Nout) {
  __shared__ _Float16 smem[2][4][8192];  // [buf][A0,A1,B0,B1][16KB]
  const int tid = threadIdx.x, lane = tid & 63, wid = tid >> 6;
  const int wm = wid >> 2, wn = wid & 3;

  int mb, nk;
  xcd_chunk_decode(&mb, &nk);
  const int m0 = mb * 256, n0 = nk * 256;
  const int NT = K >> 6;

  floatx4 acc[8][4] = {};

  auto stage_half = [&](int h) {
    if (h >= 4 * NT) return;
    const int th = h >> 2, j = h & 3, bf = th & 1;
    const int k0 = th * 64;
    const char* gb; int ld, rorig;
    if (j < 2) { gb = (const char*)A;  ld = lda; rorig = m0 + j * 128; }
    else       { gb = (const char*)Bt; ld = ldb; rorig = n0 + (j - 2) * 128; }
    _Float16* lb = &smem[bf][j][0];
#pragma unroll
    for (int i = 0; i < 2; ++i) {
      const int row = (wid * 2 + i) * 8 + (lane >> 3);
      const int gkb = ((lane & 7) * 16) ^ ((row & 7) << 4);  // inverse swizzle
      gload_lds16(gb + ((size_t)(rorig + row) * ld + k0) * 2 + gkb,
                  lb + (wid * 2 + i) * 512 + lane * 8);
    }
  };

  const unsigned smem0 = lds_off(&smem[0][0][0]);
  auto ldA = [&](int bf, int mf, int ks) -> half8 {
    const int row = mf * 16 + (lane & 15);
    const int col = (ks * 64 + ((lane >> 4) << 4)) ^ ((row & 7) << 4);
    return ds_read128(smem0 + (bf * 4 + wm) * 16384 + row * 128 + col);
  };
  auto ldB = [&](int bf, int nf, int ks) -> half8 {
    const int c = wn * 64 + nf * 16 + (lane & 15);
    const int r = c & 127;
    const int col = (ks * 64 + ((lane >> 4) << 4)) ^ ((r & 7) << 4);
    return ds_read128(smem0 + (bf * 4 + 2 + (c >> 7)) * 16384 + r * 128 + col);
  };

  stage_half(0); stage_half(1); stage_half(2); stage_half(3);
  stage_half(4 * 1 + 2); stage_half(4 * 1 + 3);
  WAITV(4); SCHED0();
  BARB();

#pragma unroll 1
  for (int t = 0; t < NT; ++t) {
    const int bf = t & 1;
    half8 a[4][2], bh[2][2], bl[2][2];
    // ---- P1
#pragma unroll
    for (int ks = 0; ks < 2; ++ks) {
#pragma unroll
      for (int m = 0; m < 4; ++m) a[m][ks] = ldA(bf, m, ks);
#pragma unroll
      for (int n = 0; n < 2; ++n) bh[n][ks] = ldB(bf, 2 + n, ks);
    }
    stage_half(4 * (t + 1) + 0);
    BARB(); WAITL0(); SCHED0();
    __builtin_amdgcn_s_setprio(1);
#pragma unroll
    for (int m = 0; m < 4; ++m)
#pragma unroll
      for (int n = 0; n < 2; ++n)
#pragma unroll
        for (int ks = 0; ks < 2; ++ks)
          acc[m][2 + n] = __builtin_amdgcn_mfma_f32_16x16x32_f16(
              a[m][ks], bh[n][ks], acc[m][2 + n], 0, 0, 0);
    __builtin_amdgcn_s_setprio(0);
    BARB();
    // ---- P2
#pragma unroll
    for (int ks = 0; ks < 2; ++ks)
#pragma unroll
      for (int n = 0; n < 2; ++n) bl[n][ks] = ldB(bf, n, ks);
    stage_half(4 * (t + 1) + 1);
    BARB(); WAITL0(); SCHED0();
    __builtin_amdgcn_s_setprio(1);
#pragma unroll
    for (int m = 0; m < 4; ++m)
#pragma unroll
      for (int n = 0; n < 2; ++n)
#pragma unroll
        for (int ks = 0; ks < 2; ++ks)
          acc[m][n] = __builtin_amdgcn_mfma_f32_16x16x32_f16(
              a[m][ks], bl[n][ks], acc[m][n], 0, 0, 0);
    __builtin_amdgcn_s_setprio(0);
    BARB();
    // ---- P3
#pragma unroll
    for (int ks = 0; ks < 2; ++ks)
#pragma unroll
      for (int m = 0; m < 4; ++m) a[m][ks] = ldA(bf, 4 + m, ks);
    stage_half(4 * (t + 2) + 2);
    BARB(); WAITL0(); SCHED0();
    __builtin_amdgcn_s_setprio(1);
#pragma unroll
    for (int m = 0; m < 4; ++m)
#pragma unroll
      for (int n = 0; n < 2; ++n)
#pragma unroll
        for (int ks = 0; ks < 2; ++ks)
          acc[4 + m][2 + n] = __builtin_amdgcn_mfma_f32_16x16x32_f16(
              a[m][ks], bh[n][ks], acc[4 + m][2 + n], 0, 0, 0);
    __builtin_amdgcn_s_setprio(0);
    BARB();
    // ---- P4
    stage_half(4 * (t + 2) + 3);
    BARB();
    __builtin_amdgcn_s_setprio(1);
#pragma unroll
    for (int m = 0; m < 4; ++m)
#pragma unroll
      for (int n = 0; n < 2; ++n)
#pragma unroll
        for (int ks = 0; ks < 2; ++ks)
          acc[4 + m][n] = __builtin_amdgcn_mfma_f32_16x16x32_f16(
              a[m][ks], bl[n][ks], acc[4 + m][n], 0, 0, 0);
    __builtin_amdgcn_s_setprio(0);
    if (t + 2 < NT) { WAITV(4); } else { WAITV(0); }
    SCHED0();
    BARB();
  }

  // epilogue: Hout = gate * relu(acc + bias)
#pragma unroll
  for (int mf = 0; mf < 8; ++mf) {
    const int gr0 = m0 + wm * 128 + mf * 16 + ((lane >> 4) << 2);
#pragma unroll
    for (int r = 0; r < 4; ++r) {
      const float g = gates[(size_t)(gr0 + r) * 8 + e];
#pragma unroll
      for (int nf = 0; nf < 4; ++nf) {
        const int gc = n0 + wn * 64 + nf * 16 + (lane & 15);
        const float v = acc[mf][nf][r] + bias[gc];
        Hout[(size_t)(gr0 + r) * Nout + gc] = (_Float16)(g * fmaxf(v, 0.0f));
      }
    }
  }
}

// ---------------------------------------------------------------------------
// GEMM2: 256x128-tile, BK=64, 2-phase pipelined, ring-of-3 LDS, NO atomics.
//   Out[m][n] += A[m][k] * Bt[n][k]^T
__global__ __launch_bounds__(512, 2) void gemm2_kernel(
    const _Float16* __restrict__ A, const _Float16* __restrict__ Bt,
    float* __restrict__ Out, int lda, int ldb, int K, int Nout) {
  __shared__ _Float16 smem[3][3][8192];  // [ring][A0,A1,B][16KB]
  const int tid = threadIdx.x, lane = tid & 63, wid = tid >> 6;
  const int wm = wid >> 2, wn = wid & 3;

  int mb, nk;
  xcd_chunk_decode(&mb, &nk);
  const int m0 = mb * 256, n0 = nk * 128;
  const int NT = K >> 6;

  floatx4 acc[8][2] = {};

  auto stage_half = [&](int tile, int j) {
    if (tile >= NT) return;
    const int bf = tile % 3;
    const int k0 = tile * 64;
    const char* gb; int ld, rorig;
    if (j < 2) { gb = (const char*)A;  ld = lda; rorig = m0 + j * 128; }
    else       { gb = (const char*)Bt; ld = ldb; rorig = n0; }
    _Float16* lb = &smem[bf][j][0];
#pragma unroll
    for (int i = 0; i < 2; ++i) {
      const int row = (wid * 2 + i) * 8 + (lane >> 3);
      const int gkb = ((lane & 7) * 16) ^ ((row & 7) << 4);  // inverse swizzle
      gload_lds16(gb + ((size_t)(rorig + row) * ld + k0) * 2 + gkb,
                  lb + (wid * 2 + i) * 512 + lane * 8);
    }
  };

  const unsigned smem0 = lds_off(&smem[0][0][0]);
  auto ldA = [&](int bf, int mf, int ks) -> half8 {
    const int row = mf * 16 + (lane & 15);
    const int col = (ks * 64 + ((lane >> 4) << 4)) ^ ((row & 7) << 4);
    return ds_read128(smem0 + (bf * 3 + wm) * 16384 + row * 128 + col);
  };
  auto ldB = [&](int bf, int nf, int ks) -> half8 {
    const int r = wn * 32 + nf * 16 + (lane & 15);
    const int col = (ks * 64 + ((lane >> 4) << 4)) ^ ((r & 7) << 4);
    return ds_read128(smem0 + (bf * 3 + 2) * 16384 + r * 128 + col);
  };

  stage_half(0, 0); stage_half(0, 1); stage_half(0, 2);
  stage_half(1, 0); stage_half(1, 1); stage_half(1, 2);
  WAITV(6); SCHED0();
  BARB();

#pragma unroll 1
  for (int t = 0; t < NT; ++t) {
    const int bf = t % 3;
    half8 a[4][2], bb[2][2];
    // ---- P1: read A m0-3 + B; stage (t+2).A0/A1; MFMA m0-3
#pragma unroll
    for (int ks = 0; ks < 2; ++ks) {
#pragma unroll
      for (int m = 0; m < 4; ++m) a[m][ks] = ldA(bf, m, ks);
#pragma unroll
      for (int n = 0; n < 2; ++n) bb[n][ks] = ldB(bf, n, ks);
    }
    stage_half(t + 2, 0); stage_half(t + 2, 1);
    BARB(); WAITL0(); SCHED0();
    __builtin_amdgcn_s_setprio(1);
#pragma unroll
    for (int m = 0; m < 4; ++m)
#pragma unroll
      for (int n = 0; n < 2; ++n)
#pragma unroll
        for (int ks = 0; ks < 2; ++ks)
          acc[m][n] = __builtin_amdgcn_mfma_f32_16x16x32_f16(
              a[m][ks], bb[n][ks], acc[m][n], 0, 0, 0);
    __builtin_amdgcn_s_setprio(0);
    BARB();
    // ---- P2: read A m4-7; stage (t+2).B; MFMA m4-7; counted gate
#pragma unroll
    for (int ks = 0; ks < 2; ++ks)
#pragma unroll
      for (int m = 0; m < 4; ++m) a[m][ks] = ldA(bf, 4 + m, ks);
    stage_half(t + 2, 2);
    BARB(); WAITL0(); SCHED0();
    __builtin_amdgcn_s_setprio(1);
#pragma unroll
    for (int m = 0; m < 4; ++m)
#pragma unroll
      for (int n = 0; n < 2; ++n)
#pragma unroll
        for (int ks = 0; ks < 2; ++ks)
          acc[4 + m][n] = __builtin_amdgcn_mfma_f32_16x16x32_f16(
              a[m][ks], bb[n][ks], acc[4 + m][n], 0, 0, 0);
    __builtin_amdgcn_s_setprio(0);
    if (t + 2 < NT) { WAITV(6); } else { WAITV(0); }
    SCHED0();
    BARB();
  }

  // epilogue: Out += acc (exclusive owner; stream order serializes experts)
#pragma unroll
  for (int mf = 0; mf < 8; ++mf) {
    const int gr0 = m0 + wm * 128 + mf * 16 + ((lane >> 4) << 2);
#pragma unroll
    for (int nf = 0; nf < 2; ++nf) {
      const int gc = n0 + wn * 32 + nf * 16 + (lane & 15);
#pragma unroll
      for (int r = 0; r < 4; ++r) {
        float* p = Out + (size_t)(gr0 + r) * Nout + gc;
        *p = *p + acc[mf][nf][r];
      }
    }
  }
}

// ---------------------------------------------------------------------------
extern "C" void kernel_launch(void* const* d_in, const int* in_sizes, int n_in,
                              void* d_out, int out_size, void* d_ws,
                              size_t ws_size, hipStream_t stream) {
  const float* x  = (const float*)d_in[0];
  const float* gw = (const float*)d_in[1];
  const float* gb = (const float*)d_in[2];
  const float* w1 = (const float*)d_in[3];
  const float* b1 = (const float*)d_in[4];
  const float* w2 = (const float*)d_in[5];
  const float* b2 = (const float*)d_in[6];
  float* out = (float*)d_out;

  const int N = 8192, D = 1024, H = 4096, E = 8;
  const size_t MB = 1ull << 20;

  char* ws = (char*)d_ws;
  float* gates  = (float*)ws;                    // 256 KB
  _Float16* x_h = (_Float16*)(ws + MB);          // 16 MB

  gates_kernel<<<N / 4, 256, 0, stream>>>(x, gw, gb, gates);
  bias_init_kernel<<<N * D / 4 / 256, 256, 0, stream>>>(gates, b2, out);
  cvt_f32_f16_kernel<<<(N * D / 8 + 255) / 256, 256, 0, stream>>>(x, x_h, N * D / 8);

  if (ws_size >= 210 * MB) {
    // big-ws path: transpose all experts up-front (2 dispatches total)
    _Float16* Hbuf = (_Float16*)(ws + 17 * MB);    // 64 MB [N][H]
    _Float16* w1t  = (_Float16*)(ws + 81 * MB);    // 64 MB [E][H][D]
    _Float16* w2t  = (_Float16*)(ws + 145 * MB);   // 64 MB [E][D][H]
    transpose_cvt_kernel<<<dim3(H / 32, D / 32, E), 256, 0, stream>>>(w1, w1t, D, H);
    transpose_cvt_kernel<<<dim3(D / 32, H / 32, E), 256, 0, stream>>>(w2, w2t, H, D);
    for (int e = 0; e < E; ++e) {
      gemm1_kernel<<<dim3(N / 256, H / 256), 512, 0, stream>>>(
          x_h, w1t + (size_t)e * H * D, b1 + (size_t)e * H, gates, e, Hbuf,
          D, D, D, H);
      gemm2_kernel<<<dim3(N / 256, D / 128), 512, 0, stream>>>(
          Hbuf, w2t + (size_t)e * D * H, out, H, H, H, D);
    }
  } else {
    // fallback (round-7 layout): per-expert transposes
    _Float16* w1t  = (_Float16*)(ws + 17 * MB);    // 8 MB [H][D]
    _Float16* w2t  = (_Float16*)(ws + 25 * MB);    // 8 MB [D][H]
    _Float16* Hbuf = (_Float16*)(ws + 33 * MB);    // 64 MB [N][H]
    for (int e = 0; e < E; ++e) {
      transpose_cvt_kernel<<<dim3(H / 32, D / 32, 1), 256, 0, stream>>>(
          w1 + (size_t)e * D * H, w1t, D, H);
      transpose_cvt_kernel<<<dim3(D / 32, H / 32, 1), 256, 0, stream>>>(
          w2 + (size_t)e * H * D, w2t, H, D);
      gemm1_kernel<<<dim3(N / 256, H / 256), 512, 0, stream>>>(
          x_h, w1t, b1 + (size_t)e * H, gates, e, Hbuf, D, D, D, H);
      gemm2_kernel<<<dim3(N / 256, D / 128), 512, 0, stream>>>(
          Hbuf, w2t, out, H, H, H, D);
    }
  }
}

// Round 9
// 1348.170 us; speedup vs baseline: 1.4582x; 1.0226x over previous
//
#include <hip/hip_runtime.h>
#include <hip/hip_bf16.h>

typedef _Float16 half8 __attribute__((ext_vector_type(8)));
typedef float floatx4 __attribute__((ext_vector_type(4)));

// ---------------------------------------------------------------------------
__device__ inline void gload_lds16(const void* g, void* l) {
  __builtin_amdgcn_global_load_lds(
      (const __attribute__((address_space(1))) unsigned int*)g,
      (__attribute__((address_space(3))) unsigned int*)l, 16, 0, 0);
}
__device__ inline unsigned lds_off(const void* p) {
  return (unsigned)(uintptr_t)(const __attribute__((address_space(3))) char*)p;
}
__device__ inline half8 ds_read128(unsigned off) {
  half8 r;
  asm volatile("ds_read_b128 %0, %1" : "=v"(r) : "v"(off));
  return r;
}
#define BARB()   __builtin_amdgcn_s_barrier()
#define WAITL0() asm volatile("s_waitcnt lgkmcnt(0)")
#define WAITV(n) asm volatile("s_waitcnt vmcnt(" #n ")")
#define SCHED0() __builtin_amdgcn_sched_barrier(0)

// Panel-chunked n-fast XCD swizzle (round-8; FETCH 283->82MB verified).
__device__ inline void xcd_chunk_decode(int* mb, int* nk) {
  const int gx = gridDim.x;
  const int nb = gx * gridDim.y;
  const int b = blockIdx.x + gx * blockIdx.y;
  const int s = (b & 7) * (nb >> 3) + (b >> 3);  // bijective
  const int PW = gx * 8;
  const int p = s / PW, r = s % PW;
  *mb = r >> 3;
  *nk = p * 8 + (r & 7);
}

// ---------------------------------------------------------------------------
__global__ __launch_bounds__(256) void gates_kernel(
    const float* __restrict__ x, const float* __restrict__ gw,
    const float* __restrict__ gb, float* __restrict__ gates) {
  const int lane = threadIdx.x & 63, wid = threadIdx.x >> 6;
  const int n = blockIdx.x * 4 + wid;
  const float* xr = x + (size_t)n * 1024;
  float xv[16];
#pragma unroll
  for (int i = 0; i < 16; ++i) xv[i] = xr[lane + i * 64];
  float logit[8];
#pragma unroll
  for (int e = 0; e < 8; ++e) {
    const float* wr = gw + (size_t)e * 1024;
    float p = 0.f;
#pragma unroll
    for (int i = 0; i < 16; ++i) p += xv[i] * wr[lane + i * 64];
#pragma unroll
    for (int off = 32; off > 0; off >>= 1) p += __shfl_xor(p, off);
    logit[e] = p + gb[e];
  }
  float mx = logit[0];
#pragma unroll
  for (int e = 1; e < 8; ++e) mx = fmaxf(mx, logit[e]);
  float s = 0.f;
#pragma unroll
  for (int e = 0; e < 8; ++e) { logit[e] = expf(logit[e] - mx); s += logit[e]; }
  if (lane < 8) gates[(size_t)n * 8 + lane] = logit[lane] / s;
}

// ---------------------------------------------------------------------------
// fallback-path: out[n][d] = sum_e g*b2 (pre-GEMM2 init)
__global__ __launch_bounds__(256) void bias_init_kernel(
    const float* __restrict__ gates, const float* __restrict__ b2,
    float* __restrict__ out) {
  const int idx = blockIdx.x * 256 + threadIdx.x;
  const int n = idx >> 8;
  const int d = (idx & 255) << 2;
  const float* g = gates + (size_t)n * 8;
  floatx4 acc = {0.f, 0.f, 0.f, 0.f};
#pragma unroll
  for (int e = 0; e < 8; ++e) {
    const float ge = g[e];
    const floatx4 b = *(const floatx4*)(b2 + (size_t)e * 1024 + d);
#pragma unroll
    for (int j = 0; j < 4; ++j) acc[j] += ge * b[j];
  }
  *(floatx4*)(out + (size_t)n * 1024 + d) = acc;
}

// ---------------------------------------------------------------------------
// main-path final: out = out + partial + sum_e gates*b2
__global__ __launch_bounds__(256) void combine_kernel(
    const float* __restrict__ gates, const float* __restrict__ b2,
    const float* __restrict__ partial, float* __restrict__ out) {
  const int idx = blockIdx.x * 256 + threadIdx.x;
  const int n = idx >> 8;
  const int d = (idx & 255) << 2;
  const float* g = gates + (size_t)n * 8;
  floatx4 acc = *(const floatx4*)(partial + (size_t)n * 1024 + d);
  const floatx4 o = *(const floatx4*)(out + (size_t)n * 1024 + d);
#pragma unroll
  for (int j = 0; j < 4; ++j) acc[j] += o[j];
#pragma unroll
  for (int e = 0; e < 8; ++e) {
    const float ge = g[e];
    const floatx4 b = *(const floatx4*)(b2 + (size_t)e * 1024 + d);
#pragma unroll
    for (int j = 0; j < 4; ++j) acc[j] += ge * b[j];
  }
  *(floatx4*)(out + (size_t)n * 1024 + d) = acc;
}

// ---------------------------------------------------------------------------
__global__ __launch_bounds__(256) void cvt_f32_f16_kernel(
    const float* __restrict__ in, _Float16* __restrict__ out, int n8) {
  const int i = blockIdx.x * 256 + threadIdx.x;
  if (i >= n8) return;
  const float4* p = (const float4*)(in + (size_t)i * 8);
  float4 a = p[0], b = p[1];
  half8 h;
  h[0] = (_Float16)a.x; h[1] = (_Float16)a.y; h[2] = (_Float16)a.z; h[3] = (_Float16)a.w;
  h[4] = (_Float16)b.x; h[5] = (_Float16)b.y; h[6] = (_Float16)b.z; h[7] = (_Float16)b.w;
  *(half8*)(out + (size_t)i * 8) = h;
}

// ---------------------------------------------------------------------------
__global__ __launch_bounds__(256) void transpose_cvt_kernel(
    const float* __restrict__ in, _Float16* __restrict__ out, int R, int C) {
  __shared__ _Float16 tile[32][33];
  const float* src = in + (size_t)blockIdx.z * R * C;
  _Float16* dst = out + (size_t)blockIdx.z * R * C;
  const int tx = threadIdx.x & 31, ty = threadIdx.x >> 5;
  const int c0 = blockIdx.x << 5, r0 = blockIdx.y << 5;
#pragma unroll
  for (int i = 0; i < 4; ++i)
    tile[ty + i * 8][tx] = (_Float16)src[(size_t)(r0 + ty + i * 8) * C + c0 + tx];
  __syncthreads();
#pragma unroll
  for (int i = 0; i < 4; ++i)
    dst[(size_t)(c0 + ty + i * 8) * R + r0 + tx] = tile[tx][ty + i * 8];
}

// ---------------------------------------------------------------------------
// Unified 256x256-tile, BK=64, 8-phase pipelined f16 MFMA GEMM (round-5
// structure, validated).  C = A[M][lda] * Bt[..][ldb]^T over k-range.
// EPI 0 (GEMM1): Hout = gate * relu(acc + bias), fp16; kb=0, n0=nk*256.
// EPI 1 (GEMM2): split-K x2 via nk: z=nk>>2 selects dest buffer
//   (z0->partial, z1->outp), n0=(nk&3)*256, kb=z*kLen; beta ? RMW : store.
//   Exclusive ownership per buffer; expert chain serialized by stream.
template <int EPI>
__global__ __launch_bounds__(512, 2) void gemm256_kernel(
    const _Float16* __restrict__ A, const _Float16* __restrict__ Bt,
    const float* __restrict__ bias, const float* __restrict__ gates, int e,
    _Float16* __restrict__ Hout, float* __restrict__ partial,
    float* __restrict__ outp, int beta, int lda, int ldb, int kLen, int Nout) {
  __shared__ _Float16 smem[2][4][8192];  // [buf][A0,A1,B0,B1][16KB]
  const int tid = threadIdx.x, lane = tid & 63, wid = tid >> 6;
  const int wm = wid >> 2, wn = wid & 3;

  int mb, nk;
  xcd_chunk_decode(&mb, &nk);
  const int m0 = mb * 256;
  int n0, kb;
  if (EPI == 1) { n0 = (nk & 3) * 256; kb = (nk >> 2) * kLen; }
  else          { n0 = nk * 256;       kb = 0; }
  const int NT = kLen >> 6;

  floatx4 acc[8][4] = {};

  auto stage_half = [&](int h) {
    if (h >= 4 * NT) return;
    const int th = h >> 2, j = h & 3, bf = th & 1;
    const int k0 = kb + th * 64;
    const char* gb; int ld, rorig;
    if (j < 2) { gb = (const char*)A;  ld = lda; rorig = m0 + j * 128; }
    else       { gb = (const char*)Bt; ld = ldb; rorig = n0 + (j - 2) * 128; }
    _Float16* lb = &smem[bf][j][0];
#pragma unroll
    for (int i = 0; i < 2; ++i) {
      const int row = (wid * 2 + i) * 8 + (lane >> 3);
      const int gkb = ((lane & 7) * 16) ^ ((row & 7) << 4);  // inverse swizzle
      gload_lds16(gb + ((size_t)(rorig + row) * ld + k0) * 2 + gkb,
                  lb + (wid * 2 + i) * 512 + lane * 8);
    }
  };

  const unsigned smem0 = lds_off(&smem[0][0][0]);
  auto ldA = [&](int bf, int mf, int ks) -> half8 {
    const int row = mf * 16 + (lane & 15);
    const int col = (ks * 64 + ((lane >> 4) << 4)) ^ ((row & 7) << 4);
    return ds_read128(smem0 + (bf * 4 + wm) * 16384 + row * 128 + col);
  };
  auto ldB = [&](int bf, int nf, int ks) -> half8 {
    const int c = wn * 64 + nf * 16 + (lane & 15);
    const int r = c & 127;
    const int col = (ks * 64 + ((lane >> 4) << 4)) ^ ((r & 7) << 4);
    return ds_read128(smem0 + (bf * 4 + 2 + (c >> 7)) * 16384 + r * 128 + col);
  };

  stage_half(0); stage_half(1); stage_half(2); stage_half(3);
  stage_half(4 * 1 + 2); stage_half(4 * 1 + 3);
  WAITV(4); SCHED0();
  BARB();

#pragma unroll 1
  for (int t = 0; t < NT; ++t) {
    const int bf = t & 1;
    half8 a[4][2], bh[2][2], bl[2][2];
    // ---- P1
#pragma unroll
    for (int ks = 0; ks < 2; ++ks) {
#pragma unroll
      for (int m = 0; m < 4; ++m) a[m][ks] = ldA(bf, m, ks);
#pragma unroll
      for (int n = 0; n < 2; ++n) bh[n][ks] = ldB(bf, 2 + n, ks);
    }
    stage_half(4 * (t + 1) + 0);
    BARB(); WAITL0(); SCHED0();
    __builtin_amdgcn_s_setprio(1);
#pragma unroll
    for (int m = 0; m < 4; ++m)
#pragma unroll
      for (int n = 0; n < 2; ++n)
#pragma unroll
        for (int ks = 0; ks < 2; ++ks)
          acc[m][2 + n] = __builtin_amdgcn_mfma_f32_16x16x32_f16(
              a[m][ks], bh[n][ks], acc[m][2 + n], 0, 0, 0);
    __builtin_amdgcn_s_setprio(0);
    BARB();
    // ---- P2
#pragma unroll
    for (int ks = 0; ks < 2; ++ks)
#pragma unroll
      for (int n = 0; n < 2; ++n) bl[n][ks] = ldB(bf, n, ks);
    stage_half(4 * (t + 1) + 1);
    BARB(); WAITL0(); SCHED0();
    __builtin_amdgcn_s_setprio(1);
#pragma unroll
    for (int m = 0; m < 4; ++m)
#pragma unroll
      for (int n = 0; n < 2; ++n)
#pragma unroll
        for (int ks = 0; ks < 2; ++ks)
          acc[m][n] = __builtin_amdgcn_mfma_f32_16x16x32_f16(
              a[m][ks], bl[n][ks], acc[m][n], 0, 0, 0);
    __builtin_amdgcn_s_setprio(0);
    BARB();
    // ---- P3
#pragma unroll
    for (int ks = 0; ks < 2; ++ks)
#pragma unroll
      for (int m = 0; m < 4; ++m) a[m][ks] = ldA(bf, 4 + m, ks);
    stage_half(4 * (t + 2) + 2);
    BARB(); WAITL0(); SCHED0();
    __builtin_amdgcn_s_setprio(1);
#pragma unroll
    for (int m = 0; m < 4; ++m)
#pragma unroll
      for (int n = 0; n < 2; ++n)
#pragma unroll
        for (int ks = 0; ks < 2; ++ks)
          acc[4 + m][2 + n] = __builtin_amdgcn_mfma_f32_16x16x32_f16(
              a[m][ks], bh[n][ks], acc[4 + m][2 + n], 0, 0, 0);
    __builtin_amdgcn_s_setprio(0);
    BARB();
    // ---- P4
    stage_half(4 * (t + 2) + 3);
    BARB();
    __builtin_amdgcn_s_setprio(1);
#pragma unroll
    for (int m = 0; m < 4; ++m)
#pragma unroll
      for (int n = 0; n < 2; ++n)
#pragma unroll
        for (int ks = 0; ks < 2; ++ks)
          acc[4 + m][n] = __builtin_amdgcn_mfma_f32_16x16x32_f16(
              a[m][ks], bl[n][ks], acc[4 + m][n], 0, 0, 0);
    __builtin_amdgcn_s_setprio(0);
    if (t + 2 < NT) { WAITV(4); } else { WAITV(0); }
    SCHED0();
    BARB();
  }

  // epilogue: D-frag col = lane&15, row = (lane>>4)*4 + r
#pragma unroll
  for (int mf = 0; mf < 8; ++mf) {
    const int gr0 = m0 + wm * 128 + mf * 16 + ((lane >> 4) << 2);
#pragma unroll
    for (int r = 0; r < 4; ++r) {
      const int gr = gr0 + r;
      float g = 0.f;
      if (EPI == 0) g = gates[(size_t)gr * 8 + e];
#pragma unroll
      for (int nf = 0; nf < 4; ++nf) {
        const int gc = n0 + wn * 64 + nf * 16 + (lane & 15);
        if (EPI == 0) {
          const float v = acc[mf][nf][r] + bias[gc];
          Hout[(size_t)gr * Nout + gc] = (_Float16)(g * fmaxf(v, 0.0f));
        } else {
          float* P = (nk >> 2) ? outp : partial;
          float* p = P + (size_t)gr * Nout + gc;
          if (beta) *p = *p + acc[mf][nf][r];
          else      *p = acc[mf][nf][r];
        }
      }
    }
  }
}

// ---------------------------------------------------------------------------
// fallback GEMM2 (round-7): 256x128-tile, ring-3, RMW epilogue
__global__ __launch_bounds__(512, 2) void gemm2_kernel(
    const _Float16* __restrict__ A, const _Float16* __restrict__ Bt,
    float* __restrict__ Out, int lda, int ldb, int K, int Nout) {
  __shared__ _Float16 smem[3][3][8192];
  const int tid = threadIdx.x, lane = tid & 63, wid = tid >> 6;
  const int wm = wid >> 2, wn = wid & 3;
  int mb, nk;
  xcd_chunk_decode(&mb, &nk);
  const int m0 = mb * 256, n0 = nk * 128;
  const int NT = K >> 6;
  floatx4 acc[8][2] = {};
  auto stage_half = [&](int tile, int j) {
    if (tile >= NT) return;
    const int bf = tile % 3;
    const int k0 = tile * 64;
    const char* gb; int ld, rorig;
    if (j < 2) { gb = (const char*)A;  ld = lda; rorig = m0 + j * 128; }
    else       { gb = (const char*)Bt; ld = ldb; rorig = n0; }
    _Float16* lb = &smem[bf][j][0];
#pragma unroll
    for (int i = 0; i < 2; ++i) {
      const int row = (wid * 2 + i) * 8 + (lane >> 3);
      const int gkb = ((lane & 7) * 16) ^ ((row & 7) << 4);
      gload_lds16(gb + ((size_t)(rorig + row) * ld + k0) * 2 + gkb,
                  lb + (wid * 2 + i) * 512 + lane * 8);
    }
  };
  const unsigned smem0 = lds_off(&smem[0][0][0]);
  auto ldA = [&](int bf, int mf, int ks) -> half8 {
    const int row = mf * 16 + (lane & 15);
    const int col = (ks * 64 + ((lane >> 4) << 4)) ^ ((row & 7) << 4);
    return ds_read128(smem0 + (bf * 3 + wm) * 16384 + row * 128 + col);
  };
  auto ldB = [&](int bf, int nf, int ks) -> half8 {
    const int r = wn * 32 + nf * 16 + (lane & 15);
    const int col = (ks * 64 + ((lane >> 4) << 4)) ^ ((r & 7) << 4);
    return ds_read128(smem0 + (bf * 3 + 2) * 16384 + r * 128 + col);
  };
  stage_half(0, 0); stage_half(0, 1); stage_half(0, 2);
  stage_half(1, 0); stage_half(1, 1); stage_half(1, 2);
  WAITV(6); SCHED0();
  BARB();
#pragma unroll 1
  for (int t = 0; t < NT; ++t) {
    const int bf = t % 3;
    half8 a[4][2], bb[2][2];
#pragma unroll
    for (int ks = 0; ks < 2; ++ks) {
#pragma unroll
      for (int m = 0; m < 4; ++m) a[m][ks] = ldA(bf, m, ks);
#pragma unroll
      for (int n = 0; n < 2; ++n) bb[n][ks] = ldB(bf, n, ks);
    }
    stage_half(t + 2, 0); stage_half(t + 2, 1);
    BARB(); WAITL0(); SCHED0();
    __builtin_amdgcn_s_setprio(1);
#pragma unroll
    for (int m = 0; m < 4; ++m)
#pragma unroll
      for (int n = 0; n < 2; ++n)
#pragma unroll
        for (int ks = 0; ks < 2; ++ks)
          acc[m][n] = __builtin_amdgcn_mfma_f32_16x16x32_f16(
              a[m][ks], bb[n][ks], acc[m][n], 0, 0, 0);
    __builtin_amdgcn_s_setprio(0);
    BARB();
#pragma unroll
    for (int ks = 0; ks < 2; ++ks)
#pragma unroll
      for (int m = 0; m < 4; ++m) a[m][ks] = ldA(bf, 4 + m, ks);
    stage_half(t + 2, 2);
    BARB(); WAITL0(); SCHED0();
    __builtin_amdgcn_s_setprio(1);
#pragma unroll
    for (int m = 0; m < 4; ++m)
#pragma unroll
      for (int n = 0; n < 2; ++n)
#pragma unroll
        for (int ks = 0; ks < 2; ++ks)
          acc[4 + m][n] = __builtin_amdgcn_mfma_f32_16x16x32_f16(
              a[m][ks], bb[n][ks], acc[4 + m][n], 0, 0, 0);
    __builtin_amdgcn_s_setprio(0);
    if (t + 2 < NT) { WAITV(6); } else { WAITV(0); }
    SCHED0();
    BARB();
  }
#pragma unroll
  for (int mf = 0; mf < 8; ++mf) {
    const int gr0 = m0 + wm * 128 + mf * 16 + ((lane >> 4) << 2);
#pragma unroll
    for (int nf = 0; nf < 2; ++nf) {
      const int gc = n0 + wn * 32 + nf * 16 + (lane & 15);
#pragma unroll
      for (int r = 0; r < 4; ++r) {
        float* p = Out + (size_t)(gr0 + r) * Nout + gc;
        *p = *p + acc[mf][nf][r];
      }
    }
  }
}

// ---------------------------------------------------------------------------
extern "C" void kernel_launch(void* const* d_in, const int* in_sizes, int n_in,
                              void* d_out, int out_size, void* d_ws,
                              size_t ws_size, hipStream_t stream) {
  const float* x  = (const float*)d_in[0];
  const float* gw = (const float*)d_in[1];
  const float* gb = (const float*)d_in[2];
  const float* w1 = (const float*)d_in[3];
  const float* b1 = (const float*)d_in[4];
  const float* w2 = (const float*)d_in[5];
  const float* b2 = (const float*)d_in[6];
  float* out = (float*)d_out;

  const int N = 8192, D = 1024, H = 4096, E = 8;
  const size_t MB = 1ull << 20;

  char* ws = (char*)d_ws;
  float* gates  = (float*)ws;                    // 256 KB
  _Float16* x_h = (_Float16*)(ws + MB);          // 16 MB

  gates_kernel<<<N / 4, 256, 0, stream>>>(x, gw, gb, gates);
  cvt_f32_f16_kernel<<<(N * D / 8 + 255) / 256, 256, 0, stream>>>(x, x_h, N * D / 8);

  if (ws_size >= 186 * MB) {
    // main path: GEMM2 = 256x256 8-phase split-Kx2 into {partial, out}
    _Float16* Hbuf   = (_Float16*)(ws + 17 * MB);   // 64 MB [N][H]
    _Float16* w2t    = (_Float16*)(ws + 81 * MB);   // 64 MB [E][D][H]
    _Float16* w1t    = (_Float16*)(ws + 145 * MB);  // 8 MB  [H][D] per-expert
    float*    partial = (float*)(ws + 153 * MB);    // 32 MB [N][D]
    transpose_cvt_kernel<<<dim3(D / 32, H / 32, E), 256, 0, stream>>>(w2, w2t, H, D);
    for (int e = 0; e < E; ++e) {
      transpose_cvt_kernel<<<dim3(H / 32, D / 32, 1), 256, 0, stream>>>(
          w1 + (size_t)e * D * H, w1t, D, H);
      // GEMM1: Hbuf = gate * relu(x.w1t^T + b1)
      gemm256_kernel<0><<<dim3(N / 256, H / 256), 512, 0, stream>>>(
          x_h, w1t, b1 + (size_t)e * H, gates, e, Hbuf, nullptr, nullptr, 0,
          D, D, D, H);
      // GEMM2: {partial,out} (+)= Hbuf.w2t^T   split-K halves, no atomics
      gemm256_kernel<1><<<dim3(N / 256, 8), 512, 0, stream>>>(
          Hbuf, w2t + (size_t)e * D * H, nullptr, nullptr, e, nullptr,
          partial, out, e > 0, H, H, H / 2, D);
    }
    combine_kernel<<<N * D / 4 / 256, 256, 0, stream>>>(gates, b2, partial, out);
  } else {
    // fallback (round-7/8 small-ws path)
    _Float16* w1t  = (_Float16*)(ws + 17 * MB);    // 8 MB [H][D]
    _Float16* w2t  = (_Float16*)(ws + 25 * MB);    // 8 MB [D][H]
    _Float16* Hbuf = (_Float16*)(ws + 33 * MB);    // 64 MB [N][H]
    bias_init_kernel<<<N * D / 4 / 256, 256, 0, stream>>>(gates, b2, out);
    for (int e = 0; e < E; ++e) {
      transpose_cvt_kernel<<<dim3(H / 32, D / 32, 1), 256, 0, stream>>>(
          w1 + (size_t)e * D * H, w1t, D, H);
      transpose_cvt_kernel<<<dim3(D / 32, H / 32, 1), 256, 0, stream>>>(
          w2 + (size_t)e * H * D, w2t, H, D);
      gemm256_kernel<0><<<dim3(N / 256, H / 256), 512, 0, stream>>>(
          x_h, w1t, b1 + (size_t)e * H, gates, e, Hbuf, nullptr, nullptr, 0,
          D, D, D, H);
      gemm2_kernel<<<dim3(N / 256, D / 128), 512, 0, stream>>>(
          Hbuf, w2t, out, H, H, H, D);
    }
  }
}